// Round 4
// baseline (469.550 us; speedup 1.0000x reference)
//
#include <hip/hip_runtime.h>
#include <stdint.h>

// ---------- scalar fast transcendentals (kept only where count is small) ----------
#define LOG2E 1.4426950408889634f
#define LN2   0.6931471805599453f

__device__ __forceinline__ float fast_softplus(float x) {
    // log(1+exp(x)) = max(x,0) + log1p(exp(-|x|))  (overflow-safe)
    float ax = fabsf(x);
    float t = LN2 * __builtin_amdgcn_logf(1.0f + __builtin_amdgcn_exp2f(-LOG2E * ax));
    return fmaxf(x, 0.0f) + t;
}
__device__ __forceinline__ float fast_ln(float x) {
    return LN2 * __builtin_amdgcn_logf(x);
}

// uniform load pinned to SGPR
__device__ __forceinline__ float uload(const float* __restrict__ p) {
    return __int_as_float(__builtin_amdgcn_readfirstlane(__float_as_int(*p)));
}

// ---------- packed fp32 (2 rows per thread -> v_pk_fma_f32) ----------
typedef float        v2f __attribute__((ext_vector_type(2)));
typedef unsigned int v2u __attribute__((ext_vector_type(2)));

__device__ __forceinline__ v2f splat(float s) { return (v2f){s, s}; }
__device__ __forceinline__ v2f vfma(v2f a, v2f b, v2f c) {
    return __builtin_elementwise_fma(a, b, c);
}

// FMA-only reciprocal: int-magic seed (~3% err) + 2 Newton steps (~1e-6 rel)
__device__ __forceinline__ v2f pk_rcp(v2f d) {
    union { v2f f; v2u u; } a;
    a.f = d;
    a.u = (v2u){0x7EF311C3u, 0x7EF311C3u} - a.u;
    v2f x = a.f;
    v2f e = vfma(-d, x, splat(1.0f));
    x = vfma(x, e, x);
    e = vfma(-d, x, splat(1.0f));
    x = vfma(x, e, x);
    return x;
}

// FMA-only tanh: Pade(5,6) on [-4.7, 4.7], clamp outside. |err| <= ~8e-4.
__device__ __forceinline__ v2f pk_tanh(v2f x) {
    x = __builtin_elementwise_min(__builtin_elementwise_max(x, splat(-4.7f)), splat(4.7f));
    v2f t = x * x;
    v2f num = vfma(t, splat(21.0f), splat(1260.0f));
    num = vfma(t, num, splat(10395.0f));
    num = num * x;
    v2f den = t + splat(210.0f);
    den = vfma(t, den, splat(4725.0f));
    den = vfma(t, den, splat(10395.0f));
    return num * pk_rcp(den);
}

// ---------- weight prep: fp32 -> fp32 (+softplus where reparameterized) ----------
// ws layout (floats):
//   [0..71]    f1_W            [72..79]   f1_b
//   [80..143]  f2_0_W          [144..151] f2_0_b
//   [152..159] sp(f2tau_W)     [160..167] sp(f2tau_b)
//   [168..231] sp(f2_1_W)      [232..239] sp(f2_1_b)
//   [240..247] sp(f2_2_W)      [248]      sp(f2_2_b)
__global__ void prep_kernel(
    const float* __restrict__ f1W,  const float* __restrict__ f1b,
    const float* __restrict__ f2tW, const float* __restrict__ f2tb,
    const float* __restrict__ f20W, const float* __restrict__ f20b,
    const float* __restrict__ f21W, const float* __restrict__ f21b,
    const float* __restrict__ f22W, const float* __restrict__ f22b,
    float* __restrict__ w)
{
    int t = threadIdx.x;
    if (t < 72) w[t]        = f1W[t];
    if (t < 8)  w[72 + t]   = f1b[t];
    if (t < 64) w[80 + t]   = f20W[t];
    if (t < 8)  w[144 + t]  = f20b[t];
    if (t < 8)  w[152 + t]  = fast_softplus(f2tW[t]);
    if (t < 8)  w[160 + t]  = fast_softplus(f2tb[t]);
    if (t < 64) w[168 + t]  = fast_softplus(f21W[t]);
    if (t < 8)  w[232 + t]  = fast_softplus(f21b[t]);
    if (t < 8)  w[240 + t]  = fast_softplus(f22W[t]);
    if (t == 0) w[248]      = fast_softplus(f22b[0]);
}

// ---------- main kernel: one thread per TWO rows (packed fp32) ----------
__global__ void __launch_bounds__(256) haz_kernel(
    const float* __restrict__ Y,
    const float* __restrict__ tau,
    const float* __restrict__ w,
    float* __restrict__ out,
    int npairs, int n)
{
    int i = blockIdx.x * blockDim.x + threadIdx.x;
    if (i >= npairs) return;
    int r0 = 2 * i;
    bool has1 = (r0 + 1) < n;
    int r1 = has1 ? r0 + 1 : r0;

    // load both Y rows (16 fp32 = 64 B each; 8x dwordx4 total, contiguous pair)
    union R { float4 v[4]; float s[16]; };
    R A, B;
    const float4* ya = (const float4*)(Y + (size_t)r0 * 16);
    const float4* yb = (const float4*)(Y + (size_t)r1 * 16);
    A.v[0] = ya[0]; A.v[1] = ya[1]; A.v[2] = ya[2]; A.v[3] = ya[3];
    B.v[0] = yb[0]; B.v[1] = yb[1]; B.v[2] = yb[2]; B.v[3] = yb[3];

    // yd[t] = log(diff + 0.1) for both rows (cols 3..14 -> diffs 0..10)
    v2f yd[11];
    #pragma unroll
    for (int j = 0; j < 11; ++j) {
        yd[j] = (v2f){ fast_ln(A.s[4 + j] - A.s[3 + j] + 0.1f),
                       fast_ln(B.s[4 + j] - B.s[3 + j] + 0.1f) };
    }

    // pin f1 weights to SGPRs
    float f1W[72], f1b[8];
    #pragma unroll
    for (int k = 0; k < 72; ++k) f1W[k] = uload(w + k);
    #pragma unroll
    for (int k = 0; k < 8; ++k)  f1b[k] = uload(w + 72 + k);

    // recurrent f1: 11 steps of tanh(Linear(9->8)), both rows packed
    v2f flow[8];
    #pragma unroll
    for (int k = 0; k < 8; ++k) flow[k] = splat(0.0f);

    #pragma unroll
    for (int t = 0; t < 11; ++t) {
        v2f nf[8];
        #pragma unroll
        for (int o = 0; o < 8; ++o) {
            v2f acc = splat(f1b[o]);
            #pragma unroll
            for (int k = 0; k < 8; ++k)
                acc = vfma(splat(f1W[o * 9 + k]), flow[k], acc);
            acc = vfma(splat(f1W[o * 9 + 8]), yd[t], acc);
            nf[o] = pk_tanh(acc);
        }
        #pragma unroll
        for (int o = 0; o < 8; ++o) flow[o] = nf[o];
    }

    // f2 layer 0: tanh(flow @ W0.T + b0 + tau*sp(Wt) + sp(bt))
    v2f tv = (v2f){ tau[r0], tau[r1] };
    v2f h[8];
    #pragma unroll
    for (int o = 0; o < 8; ++o) {
        v2f acc = vfma(tv, splat(uload(w + 152 + o)),
                       splat(uload(w + 144 + o) + uload(w + 160 + o)));
        #pragma unroll
        for (int k = 0; k < 8; ++k)
            acc = vfma(splat(uload(w + 80 + o * 8 + k)), flow[k], acc);
        h[o] = pk_tanh(acc);
    }
    // f2 layer 1: tanh(h @ sp(W1).T + sp(b1))
    v2f g[8];
    #pragma unroll
    for (int o = 0; o < 8; ++o) {
        v2f acc = splat(uload(w + 232 + o));
        #pragma unroll
        for (int k = 0; k < 8; ++k)
            acc = vfma(splat(uload(w + 168 + o * 8 + k)), h[k], acc);
        g[o] = pk_tanh(acc);
    }
    // output layer + softplus
    v2f z = splat(uload(w + 248));
    #pragma unroll
    for (int k = 0; k < 8; ++k)
        z = vfma(splat(uload(w + 240 + k)), g[k], z);

    float o0 = fast_softplus(z.x);
    float o1 = fast_softplus(z.y);
    if (has1) {
        ((float2*)out)[i] = make_float2(o0, o1);   // 8B coalesced store
    } else {
        out[r0] = o0;
    }
}

extern "C" void kernel_launch(void* const* d_in, const int* in_sizes, int n_in,
                              void* d_out, int out_size, void* d_ws, size_t ws_size,
                              hipStream_t stream)
{
    const float* Y   = (const float*)d_in[0];
    const float* tau = (const float*)d_in[1];
    float* w = (float*)d_ws;
    float* out = (float*)d_out;
    int n = in_sizes[1];  // tau_vec has N elements
    int npairs = (n + 1) / 2;

    prep_kernel<<<1, 128, 0, stream>>>(
        (const float*)d_in[2],  (const float*)d_in[3],
        (const float*)d_in[4],  (const float*)d_in[5],
        (const float*)d_in[6],  (const float*)d_in[7],
        (const float*)d_in[8],  (const float*)d_in[9],
        (const float*)d_in[10], (const float*)d_in[11],
        w);

    haz_kernel<<<(npairs + 255) / 256, 256, 0, stream>>>(Y, tau, w, out, npairs, n);
}

// Round 5
// 464.057 us; speedup vs baseline: 1.0118x; 1.0118x over previous
//
#include <hip/hip_runtime.h>
#include <stdint.h>

#define LOG2E 1.4426950408889634f
#define LN2   0.6931471805599453f

// ---------- scalar trans (kept only where count is tiny: 22 logs + 2 softplus / thread) ----------
__device__ __forceinline__ float fast_softplus(float x) {
    float ax = fabsf(x);
    float t = LN2 * __builtin_amdgcn_logf(1.0f + __builtin_amdgcn_exp2f(-LOG2E * ax));
    return fmaxf(x, 0.0f) + t;
}
__device__ __forceinline__ float fast_ln(float x) {
    return LN2 * __builtin_amdgcn_logf(x);
}

// uniform load pinned to SGPR
__device__ __forceinline__ float uload(const float* __restrict__ p) {
    return __int_as_float(__builtin_amdgcn_readfirstlane(__float_as_int(*p)));
}

// ---------- trans-free f32 tanh: Pade(5,6) + magic rcp + 2 Newton ----------
__device__ __forceinline__ float tanh_pade(float x) {
    x = fminf(fmaxf(x, -4.7f), 4.7f);
    float t = x * x;
    float num = fmaf(t, 21.0f, 1260.0f);
    num = fmaf(t, num, 10395.0f);
    num *= x;
    float den = t + 210.0f;
    den = fmaf(t, den, 4725.0f);
    den = fmaf(t, den, 10395.0f);
    float r = __int_as_float(0x7EF311C3u - __float_as_uint(den));
    r = fmaf(r, fmaf(-den, r, 1.0f), r);
    r = fmaf(r, fmaf(-den, r, 1.0f), r);
    return num * r;
}

// ---------- packed f16 (2 rows per thread -> v_pk_fma_f16, true 2x rate) ----------
typedef _Float16 v2h __attribute__((ext_vector_type(2)));

__device__ __forceinline__ v2h hfma(v2h a, v2h b, v2h c) {
    return __builtin_elementwise_fma(a, b, c);
}
__device__ __forceinline__ v2h hsplat(float s) {
    _Float16 h = (_Float16)s;
    return (v2h){h, h};
}

// trans-free packed tanh: normalized Pade(5,6) (coeffs /10395, all intermediates <=22, f16-safe)
// + packed int-magic rcp (no cross-half borrow: den in [1,22] -> bits in [0x3C00,0x4D7C] < 0x7799)
__device__ __forceinline__ v2h pk_tanh(v2h x) {
    const v2h ONE = hsplat(1.0f);
    x = __builtin_elementwise_min(__builtin_elementwise_max(x, hsplat(-4.7f)), hsplat(4.7f));
    v2h t = x * x;
    v2h num = hfma(t, hsplat(0.00202020f), hsplat(0.12121212f));
    num = hfma(t, num, ONE);
    num = num * x;
    v2h den = hfma(t, hsplat(9.62001e-5f), hsplat(0.02020202f));
    den = hfma(t, den, hsplat(0.45454545f));
    den = hfma(t, den, ONE);
    union { v2h h; unsigned int u; } a;
    a.h = den;
    a.u = 0x77997799u - a.u;          // per-half magic seed, ~5% err
    v2h r = a.h;
    r = hfma(r, hfma(-den, r, ONE), r);   // Newton 1
    r = hfma(r, hfma(-den, r, ONE), r);   // Newton 2 -> f16 resolution
    return num * r;
}

// ---------- weight prep ----------
// ws layout (floats):
//   [0..71]    f1_W as dup-packed half2   [72..79]  f1_b dup-packed half2
//   [80..143]  f2_0_W f32                 [144..151] f2_0_b f32
//   [152..159] sp(f2tau_W)                [160..167] sp(f2tau_b)
//   [168..231] sp(f2_1_W)                 [232..239] sp(f2_1_b)
//   [240..247] sp(f2_2_W)                 [248]      sp(f2_2_b)
__global__ void prep_kernel(
    const float* __restrict__ f1W,  const float* __restrict__ f1b,
    const float* __restrict__ f2tW, const float* __restrict__ f2tb,
    const float* __restrict__ f20W, const float* __restrict__ f20b,
    const float* __restrict__ f21W, const float* __restrict__ f21b,
    const float* __restrict__ f22W, const float* __restrict__ f22b,
    float* __restrict__ w)
{
    int t = threadIdx.x;
    union { v2h h; float f; } p;
    if (t < 72) { _Float16 h = (_Float16)f1W[t]; p.h = (v2h){h, h}; w[t] = p.f; }
    if (t < 8)  { _Float16 h = (_Float16)f1b[t]; p.h = (v2h){h, h}; w[72 + t] = p.f; }
    if (t < 64) w[80 + t]   = f20W[t];
    if (t < 8)  w[144 + t]  = f20b[t];
    if (t < 8)  w[152 + t]  = fast_softplus(f2tW[t]);
    if (t < 8)  w[160 + t]  = fast_softplus(f2tb[t]);
    if (t < 64) w[168 + t]  = fast_softplus(f21W[t]);
    if (t < 8)  w[232 + t]  = fast_softplus(f21b[t]);
    if (t < 8)  w[240 + t]  = fast_softplus(f22W[t]);
    if (t == 0) w[248]      = fast_softplus(f22b[0]);
}

// f32 f2 head (high-gain layers kept in f32): flow[8] -> scalar hazard
__device__ __forceinline__ float f2_head(const float* __restrict__ w,
                                         const float fl[8], float tv) {
    float h[8];
    #pragma unroll
    for (int o = 0; o < 8; ++o) {
        float acc = uload(w + 144 + o) + tv * uload(w + 152 + o) + uload(w + 160 + o);
        #pragma unroll
        for (int k = 0; k < 8; ++k) acc = fmaf(uload(w + 80 + o * 8 + k), fl[k], acc);
        h[o] = tanh_pade(acc);
    }
    float g[8];
    #pragma unroll
    for (int o = 0; o < 8; ++o) {
        float acc = uload(w + 232 + o);
        #pragma unroll
        for (int k = 0; k < 8; ++k) acc = fmaf(uload(w + 168 + o * 8 + k), h[k], acc);
        g[o] = tanh_pade(acc);
    }
    float z = uload(w + 248);
    #pragma unroll
    for (int k = 0; k < 8; ++k) z = fmaf(uload(w + 240 + k), g[k], z);
    return fast_softplus(z);
}

// ---------- main kernel: one thread per TWO rows, f1 recurrence in packed f16 ----------
__global__ void __launch_bounds__(256) haz_kernel(
    const float* __restrict__ Y,
    const float* __restrict__ tau,
    const float* __restrict__ w,
    float* __restrict__ out,
    int npairs, int n)
{
    int i = blockIdx.x * blockDim.x + threadIdx.x;
    if (i >= npairs) return;
    int r0 = 2 * i;
    bool has1 = (r0 + 1) < n;
    int r1 = has1 ? r0 + 1 : r0;

    union R { float4 v[4]; float s[16]; };
    R A, B;
    const float4* ya = (const float4*)(Y + (size_t)r0 * 16);
    const float4* yb = (const float4*)(Y + (size_t)r1 * 16);
    A.v[0] = ya[0]; A.v[1] = ya[1]; A.v[2] = ya[2]; A.v[3] = ya[3];
    B.v[0] = yb[0]; B.v[1] = yb[1]; B.v[2] = yb[2]; B.v[3] = yb[3];

    // yd[t] = log(diff+0.1) in f32, packed to f16 pair (rowA, rowB)
    v2h yd[11];
    #pragma unroll
    for (int j = 0; j < 11; ++j) {
        float da = fast_ln(A.s[4 + j] - A.s[3 + j] + 0.1f);
        float db = fast_ln(B.s[4 + j] - B.s[3 + j] + 0.1f);
        yd[j] = (v2h){(_Float16)da, (_Float16)db};
    }

    // f1 weights: dup-packed half2, pinned to SGPRs via readfirstlane
    v2h Wk[72], Bk[8];
    #pragma unroll
    for (int k = 0; k < 72; ++k) {
        union { float f; v2h h; } c; c.f = uload(w + k); Wk[k] = c.h;
    }
    #pragma unroll
    for (int k = 0; k < 8; ++k) {
        union { float f; v2h h; } c; c.f = uload(w + 72 + k); Bk[k] = c.h;
    }

    // recurrent f1: 11 steps of tanh(Linear(9->8)), both rows packed in half2
    v2h flow[8];
    #pragma unroll
    for (int k = 0; k < 8; ++k) flow[k] = hsplat(0.0f);

    #pragma unroll
    for (int t = 0; t < 11; ++t) {
        v2h nf[8];
        #pragma unroll
        for (int o = 0; o < 8; ++o) {
            v2h acc = Bk[o];
            #pragma unroll
            for (int k = 0; k < 8; ++k) acc = hfma(Wk[o * 9 + k], flow[k], acc);
            acc = hfma(Wk[o * 9 + 8], yd[t], acc);
            nf[o] = pk_tanh(acc);
        }
        #pragma unroll
        for (int o = 0; o < 8; ++o) flow[o] = nf[o];
    }

    // unpack to f32 and run the high-gain f2 head per row in f32
    float flA[8], flB[8];
    #pragma unroll
    for (int k = 0; k < 8; ++k) { flA[k] = (float)flow[k].x; flB[k] = (float)flow[k].y; }

    float o0 = f2_head(w, flA, tau[r0]);
    float o1 = f2_head(w, flB, tau[r1]);

    if (has1) {
        ((float2*)out)[i] = make_float2(o0, o1);
    } else {
        out[r0] = o0;
    }
}

extern "C" void kernel_launch(void* const* d_in, const int* in_sizes, int n_in,
                              void* d_out, int out_size, void* d_ws, size_t ws_size,
                              hipStream_t stream)
{
    const float* Y   = (const float*)d_in[0];
    const float* tau = (const float*)d_in[1];
    float* w = (float*)d_ws;
    float* out = (float*)d_out;
    int n = in_sizes[1];
    int npairs = (n + 1) / 2;

    prep_kernel<<<1, 128, 0, stream>>>(
        (const float*)d_in[2],  (const float*)d_in[3],
        (const float*)d_in[4],  (const float*)d_in[5],
        (const float*)d_in[6],  (const float*)d_in[7],
        (const float*)d_in[8],  (const float*)d_in[9],
        (const float*)d_in[10], (const float*)d_in[11],
        w);

    haz_kernel<<<(npairs + 255) / 256, 256, 0, stream>>>(Y, tau, w, out, npairs, n);
}

// Round 6
// 431.716 us; speedup vs baseline: 1.0876x; 1.0749x over previous
//
#include <hip/hip_runtime.h>
#include <hip/hip_fp16.h>
#include <stdint.h>

#define LOG2E 1.4426950408889634f
#define LN2   0.6931471805599453f

// ---------- scalar trans helpers ----------
__device__ __forceinline__ float fast_softplus(float x) {
    float ax = fabsf(x);
    float t = LN2 * __builtin_amdgcn_logf(1.0f + __builtin_amdgcn_exp2f(-LOG2E * ax));
    return fmaxf(x, 0.0f) + t;
}
__device__ __forceinline__ float fast_ln(float x) {
    return LN2 * __builtin_amdgcn_logf(x);
}
__device__ __forceinline__ float fast_tanh(float x) {
    // tanh(x) = 1 - 2/(exp(2x)+1); trans-pipe version (used only in f2: 16/row)
    float e = __builtin_amdgcn_exp2f(x * (2.0f * LOG2E));
    return 1.0f - 2.0f * __builtin_amdgcn_rcpf(e + 1.0f);
}

// uniform load pinned to SGPR (returns raw bits)
__device__ __forceinline__ unsigned int uload_bits(const float* __restrict__ p) {
    return (unsigned int)__builtin_amdgcn_readfirstlane(__float_as_int(*p));
}
__device__ __forceinline__ float uload(const float* __restrict__ p) {
    return __int_as_float(__builtin_amdgcn_readfirstlane(__float_as_int(*p)));
}

// ---------- packed f16 tanh: normalized Pade(5,6), no clamp (|x|<=3.7 by construction),
// magic-seed reciprocal + 1 Newton. ~11 VOP3P instructions, no trans. ----------
__device__ __forceinline__ __half2 pk_tanh(__half2 x) {
    const __half2 ONE = __float2half2_rn(1.0f);
    __half2 t   = __hmul2(x, x);                                     // t = x^2, t <= ~13.5
    __half2 num = __hfma2(t, __float2half2_rn(0.00202020f),
                             __float2half2_rn(0.12121212f));
    num = __hfma2(t, num, ONE);
    num = __hmul2(num, x);
    __half2 den = __hfma2(t, __float2half2_rn(9.62001e-5f),
                             __float2half2_rn(0.02020202f));
    den = __hfma2(t, den, __float2half2_rn(0.45454545f));
    den = __hfma2(t, den, ONE);                                      // den in [1, ~11.1]
    // per-half magic rcp seed: den bits <= 0x4990 < 0x7799 -> no cross-half borrow
    unsigned int du = __builtin_bit_cast(unsigned int, den);
    __half2 r = __builtin_bit_cast(__half2, 0x77997799u - du);       // ~5% err
    r = __hfma2(r, __hfma2(__hneg2(den), r, ONE), r);                // Newton -> ~0.2%
    return __hmul2(num, r);
}

// ---------- weight prep ----------
// ws layout (floats):
//   [0..71]    f1_W dup-packed half2      [72..79]   f1_b dup-packed half2
//   [80..143]  f2_0_W f32                 [144..151] f2_0_b f32
//   [152..159] sp(f2tau_W)                [160..167] sp(f2tau_b)
//   [168..231] sp(f2_1_W)                 [232..239] sp(f2_1_b)
//   [240..247] sp(f2_2_W)                 [248]      sp(f2_2_b)
__global__ void prep_kernel(
    const float* __restrict__ f1W,  const float* __restrict__ f1b,
    const float* __restrict__ f2tW, const float* __restrict__ f2tb,
    const float* __restrict__ f20W, const float* __restrict__ f20b,
    const float* __restrict__ f21W, const float* __restrict__ f21b,
    const float* __restrict__ f22W, const float* __restrict__ f22b,
    float* __restrict__ w)
{
    int t = threadIdx.x;
    if (t < 72) {
        __half2 h = __float2half2_rn(f1W[t]);
        w[t] = __builtin_bit_cast(float, h);
    }
    if (t < 8) {
        __half2 h = __float2half2_rn(f1b[t]);
        w[72 + t] = __builtin_bit_cast(float, h);
    }
    if (t < 64) w[80 + t]   = f20W[t];
    if (t < 8)  w[144 + t]  = f20b[t];
    if (t < 8)  w[152 + t]  = fast_softplus(f2tW[t]);
    if (t < 8)  w[160 + t]  = fast_softplus(f2tb[t]);
    if (t < 64) w[168 + t]  = fast_softplus(f21W[t]);
    if (t < 8)  w[232 + t]  = fast_softplus(f21b[t]);
    if (t < 8)  w[240 + t]  = fast_softplus(f22W[t]);
    if (t == 0) w[248]      = fast_softplus(f22b[0]);
}

// f32 f2 head (high-gain layers stay f32; tanh on trans pipe): flow[8] -> hazard
__device__ __forceinline__ float f2_head(const float* __restrict__ w,
                                         const float fl[8], float tv) {
    float h[8];
    #pragma unroll
    for (int o = 0; o < 8; ++o) {
        float acc = uload(w + 144 + o) + tv * uload(w + 152 + o) + uload(w + 160 + o);
        #pragma unroll
        for (int k = 0; k < 8; ++k) acc = fmaf(uload(w + 80 + o * 8 + k), fl[k], acc);
        h[o] = fast_tanh(acc);
    }
    float g[8];
    #pragma unroll
    for (int o = 0; o < 8; ++o) {
        float acc = uload(w + 232 + o);
        #pragma unroll
        for (int k = 0; k < 8; ++k) acc = fmaf(uload(w + 168 + o * 8 + k), h[k], acc);
        g[o] = fast_tanh(acc);
    }
    float z = uload(w + 248);
    #pragma unroll
    for (int k = 0; k < 8; ++k) z = fmaf(uload(w + 240 + k), g[k], z);
    return fast_softplus(z);
}

// ---------- main kernel: one thread per TWO rows, f1 recurrence in v_pk_*_f16 ----------
__global__ void __launch_bounds__(256) haz_kernel(
    const float* __restrict__ Y,
    const float* __restrict__ tau,
    const float* __restrict__ w,
    float* __restrict__ out,
    int npairs, int n)
{
    int i = blockIdx.x * blockDim.x + threadIdx.x;
    if (i >= npairs) return;
    int r0 = 2 * i;
    bool has1 = (r0 + 1) < n;
    int r1 = has1 ? r0 + 1 : r0;

    union R { float4 v[4]; float s[16]; };
    R A, B;
    const float4* ya = (const float4*)(Y + (size_t)r0 * 16);
    const float4* yb = (const float4*)(Y + (size_t)r1 * 16);
    A.v[0] = ya[0]; A.v[1] = ya[1]; A.v[2] = ya[2]; A.v[3] = ya[3];
    B.v[0] = yb[0]; B.v[1] = yb[1]; B.v[2] = yb[2]; B.v[3] = yb[3];

    // yd[t] = log(diff+0.1) computed in f32 (trans pipe), packed (rowA, rowB)
    __half2 yd[11];
    #pragma unroll
    for (int j = 0; j < 11; ++j) {
        float da = fast_ln(A.s[4 + j] - A.s[3 + j] + 0.1f);
        float db = fast_ln(B.s[4 + j] - B.s[3 + j] + 0.1f);
        yd[j] = __halves2half2(__float2half(da), __float2half(db));
    }

    // f1 weights: dup-packed half2 bits pinned to SGPRs
    unsigned int Wk[72], Bk[8];
    #pragma unroll
    for (int k = 0; k < 72; ++k) Wk[k] = uload_bits(w + k);
    #pragma unroll
    for (int k = 0; k < 8; ++k)  Bk[k] = uload_bits(w + 72 + k);

    // recurrent f1: 11 steps of tanh(Linear(9->8)), both rows packed in half2
    __half2 flow[8];
    #pragma unroll
    for (int k = 0; k < 8; ++k) flow[k] = __float2half2_rn(0.0f);

    #pragma unroll
    for (int t = 0; t < 11; ++t) {
        __half2 nf[8];
        #pragma unroll
        for (int o = 0; o < 8; ++o) {
            __half2 acc = __builtin_bit_cast(__half2, Bk[o]);
            #pragma unroll
            for (int k = 0; k < 8; ++k)
                acc = __hfma2(__builtin_bit_cast(__half2, Wk[o * 9 + k]), flow[k], acc);
            acc = __hfma2(__builtin_bit_cast(__half2, Wk[o * 9 + 8]), yd[t], acc);
            nf[o] = pk_tanh(acc);
        }
        #pragma unroll
        for (int o = 0; o < 8; ++o) flow[o] = nf[o];
    }

    // unpack to f32; run the high-gain f2 head per row in f32
    float flA[8], flB[8];
    #pragma unroll
    for (int k = 0; k < 8; ++k) {
        flA[k] = __low2float(flow[k]);
        flB[k] = __high2float(flow[k]);
    }

    float o0 = f2_head(w, flA, tau[r0]);
    float o1 = f2_head(w, flB, tau[r1]);

    if (has1) {
        ((float2*)out)[i] = make_float2(o0, o1);
    } else {
        out[r0] = o0;
    }
}

extern "C" void kernel_launch(void* const* d_in, const int* in_sizes, int n_in,
                              void* d_out, int out_size, void* d_ws, size_t ws_size,
                              hipStream_t stream)
{
    const float* Y   = (const float*)d_in[0];
    const float* tau = (const float*)d_in[1];
    float* w = (float*)d_ws;
    float* out = (float*)d_out;
    int n = in_sizes[1];
    int npairs = (n + 1) / 2;

    prep_kernel<<<1, 128, 0, stream>>>(
        (const float*)d_in[2],  (const float*)d_in[3],
        (const float*)d_in[4],  (const float*)d_in[5],
        (const float*)d_in[6],  (const float*)d_in[7],
        (const float*)d_in[8],  (const float*)d_in[9],
        (const float*)d_in[10], (const float*)d_in[11],
        w);

    haz_kernel<<<(npairs + 255) / 256, 256, 0, stream>>>(Y, tau, w, out, npairs, n);
}